// Round 6
// baseline (478.539 us; speedup 1.0000x reference)
//
#include <hip/hip_runtime.h>
#include <cstdint>

#define B_SZ 16
#define SEQ 1024
#define DIM 768
#define NH 12
#define HD 64
#define M_TOTAL (B_SZ*SEQ)       // 16384
#define QKV_OUT (3*DIM)          // 2304
#define EXP2_SCALE 0.18033688011f   // (1/8) * log2(e)

typedef _Float16 f16;
typedef __attribute__((ext_vector_type(8))) f16 f16x8;
typedef __attribute__((ext_vector_type(4))) f16 f16x4;
typedef __attribute__((ext_vector_type(2))) __fp16 pk16x2;   // cvt_pkrtz native type
typedef __attribute__((ext_vector_type(4))) short s4_t;
typedef __attribute__((ext_vector_type(4))) float f32x4;
typedef unsigned int u32;
typedef const __attribute__((address_space(1))) u32* gas_t;
typedef __attribute__((address_space(3))) u32* las_t;

union U4 { pk16x2 h2[2]; f16x4 v; };
union HS { f16 h; short s; };

__device__ __forceinline__ void async16(const void* g, void* l) {
    __builtin_amdgcn_global_load_lds((gas_t)g, (las_t)l, 16, 0, 0);
}
__device__ __forceinline__ f32x4 mfma32h(f16x8 a, f16x8 b, f32x4 c) {
    return __builtin_amdgcn_mfma_f32_16x16x32_f16(a, b, c, 0, 0, 0);
}
__device__ __forceinline__ f32x4 mfma16h(f16x4 a, f16x4 b, f32x4 c) {
    return __builtin_amdgcn_mfma_f32_16x16x16f16(a, b, c, 0, 0, 0);
}
__device__ __forceinline__ f16x8 ldfragh(const short* p) {
    return *(const f16x8*)p;
}

// ---------------- fp32 -> fp16 conversion of x, w_qkv, w_proj ----------------
__global__ void cvt_kernel(const float* __restrict__ x, const float* __restrict__ wq,
                           const float* __restrict__ wp,
                           short* __restrict__ xb, short* __restrict__ wqb, short* __restrict__ wpb) {
    const long nx = (long)M_TOTAL * DIM / 4;
    const long nq = (long)QKV_OUT * DIM / 4;
    const long np = (long)DIM * DIM / 4;
    const long total = nx + nq + np;
    for (long i = (long)blockIdx.x * blockDim.x + threadIdx.x; i < total;
         i += (long)gridDim.x * blockDim.x) {
        const float4* src; short* dst; long off;
        if (i < nx)            { src = (const float4*)x;  dst = xb;  off = i; }
        else if (i < nx + nq)  { src = (const float4*)wq; dst = wqb; off = i - nx; }
        else                   { src = (const float4*)wp; dst = wpb; off = i - nx - nq; }
        float4 v = src[off];
        U4 u;
        u.h2[0] = __builtin_amdgcn_cvt_pkrtz(v.x, v.y);
        u.h2[1] = __builtin_amdgcn_cvt_pkrtz(v.z, v.w);
        *(f16x4*)(dst + off * 4) = u.v;
    }
}

// ---------------- m97-style f16 GEMM:  C[M,N] = A[M,K] * Bm[N,K]^T ----------------
// EPI 0: scatter to Q/K [b][h][n][hd] and V TRANSPOSED [b][h][hd][n]
// EPI 1: add bias, write fp32 to Cout [M,N]
template<int EPI, int N, int K>
__global__ __launch_bounds__(256) void gemm_bt(const short* __restrict__ A,
                                               const short* __restrict__ Bm,
                                               short* __restrict__ Cq, short* __restrict__ Ck,
                                               short* __restrict__ Cv,
                                               float* __restrict__ Cout,
                                               const float* __restrict__ bias) {
    __shared__ short As[128 * 32];
    __shared__ short Bs[128 * 32];
    const int tid = threadIdx.x;
    const int w = tid >> 6, l = tid & 63, quad = l >> 4, l15 = l & 15;
    const int wr = w >> 1, wc = w & 1;
    const int m0 = blockIdx.y * 128, n0 = blockIdx.x * 128;

    f32x4 acc[4][4];
#pragma unroll
    for (int i = 0; i < 4; ++i)
#pragma unroll
        for (int j = 0; j < 4; ++j) acc[i][j] = (f32x4){0.f, 0.f, 0.f, 0.f};

    for (int kt = 0; kt < K / 32; ++kt) {
#pragma unroll
        for (int i = 0; i < 2; ++i) {
            int c = i * 256 + tid;
            int row = c >> 2, kc = c & 3;
            async16(&A[(size_t)(m0 + row) * K + kt * 32 + kc * 8], &As[c * 8]);
            async16(&Bm[(size_t)(n0 + row) * K + kt * 32 + kc * 8], &Bs[c * 8]);
        }
        __syncthreads();
        f16x8 af[4], bf[4];
#pragma unroll
        for (int rt = 0; rt < 4; ++rt)
            af[rt] = ldfragh(&As[(wr * 64 + rt * 16 + l15) * 32 + quad * 8]);
#pragma unroll
        for (int ct = 0; ct < 4; ++ct)
            bf[ct] = ldfragh(&Bs[(wc * 64 + ct * 16 + l15) * 32 + quad * 8]);
#pragma unroll
        for (int rt = 0; rt < 4; ++rt)
#pragma unroll
            for (int ct = 0; ct < 4; ++ct)
                acc[rt][ct] = mfma32h(af[rt], bf[ct], acc[rt][ct]);
        __syncthreads();
    }

#pragma unroll
    for (int rt = 0; rt < 4; ++rt) {
#pragma unroll
        for (int ct = 0; ct < 4; ++ct) {
            int col = n0 + wc * 64 + ct * 16 + l15;
            if (EPI == 0) {
                int s = col / DIM;
                int h = (col - s * DIM) >> 6, hd = col & 63;
                int mbase = m0 + wr * 64 + rt * 16 + quad * 4;
                int b = mbase >> 10, nn = mbase & 1023;
                if (s == 2) {
                    // V transposed: [b][h][hd][n]; 4 consecutive n -> one 8B store
                    U4 u;
                    u.h2[0] = __builtin_amdgcn_cvt_pkrtz(acc[rt][ct][0], acc[rt][ct][1]);
                    u.h2[1] = __builtin_amdgcn_cvt_pkrtz(acc[rt][ct][2], acc[rt][ct][3]);
                    *(f16x4*)&Cv[(((size_t)b * NH + h) * HD + hd) * SEQ + nn] = u.v;
                } else {
                    short* dst = (s == 0) ? Cq : Ck;
#pragma unroll
                    for (int r = 0; r < 4; ++r) {
                        HS t; t.h = (f16)acc[rt][ct][r];
                        dst[(((size_t)b * NH + h) * SEQ + nn + r) * HD + hd] = t.s;
                    }
                }
            } else {
                float bv = bias[col];
#pragma unroll
                for (int r = 0; r < 4; ++r) {
                    int m = m0 + wr * 64 + rt * 16 + quad * 4 + r;
                    Cout[(size_t)m * N + col] = acc[rt][ct][r] + bv;
                }
            }
        }
    }
}

// ---------------- attention: pure-register flash, no LDS, no barriers ----------------
// Trick: compute S^T = K*Q^T. The 16x16 C/D layout (row=kv=quad*4+r, col=q=l15) is
// EXACTLY the B-operand layout of v_mfma_f32_16x16x16f16 (B[k=quad*4+j][n=l15]), so
// exp(S^T) feeds the PV MFMA directly from registers: O^T[hd][q] += V^T-frag * P^T-frag.
// Each wave owns 32 q rows independently; WG = 128 q rows; XCD swizzle keeps each
// head's K/V (256 KB, f16) L2-resident. Row sums: 2x shfl_xor over quads. No spill
// risk: no launch_bounds wave cap (round-4 lesson: forcing 8 blk/CU spilled 160 MB).
__global__ __launch_bounds__(256) void attn_kernel(const short* __restrict__ Q,
                                                   const short* __restrict__ Km,
                                                   const short* __restrict__ Vt,
                                                   short* __restrict__ O) {
    const int tid = threadIdx.x;
    const int w = tid >> 6, l = tid & 63, quad = l >> 4, l15 = l & 15;
    const int bid = blockIdx.x;
    const int xcd = bid & 7, kk = bid >> 3;
    const int head = xcd + 8 * (kk >> 3);        // 0..191, 8 q-chunks/head per XCD
    const int q0 = (kk & 7) * 128 + w * 32;      // this wave's 32 q rows
    const int b = head / NH, h = head - b * NH;
    const short* Qp = Q + (size_t)head * (SEQ * HD);
    const short* Kp = Km + (size_t)head * (SEQ * HD);
    const short* Vp = Vt + (size_t)head * (SEQ * HD);   // [hd][n]

    // Q as B-operand fragments: B[n=q=l15][k=hd=quad*8+j], two hd-halves, two q-tiles
    f16x8 qf[2][2];
#pragma unroll
    for (int qt = 0; qt < 2; ++qt)
#pragma unroll
        for (int hf = 0; hf < 2; ++hf)
            qf[qt][hf] = *(const f16x8*)&Qp[(q0 + qt * 16 + l15) * HD + hf * 32 + quad * 8];

    f32x4 oacc[2][4];
#pragma unroll
    for (int qt = 0; qt < 2; ++qt)
#pragma unroll
        for (int ht = 0; ht < 4; ++ht) oacc[qt][ht] = (f32x4){0.f, 0.f, 0.f, 0.f};
    float psum[2] = {0.f, 0.f};

    // K A-frag: A[m=kv_local=l15][k=hd=quad*8+j];  V^T A-frag: A[m=hd=l15][k=kv=quad*4+j]
    const short* kb = &Kp[l15 * HD + quad * 8];
    const short* vb = &Vp[l15 * SEQ + quad * 4];

    f16x8 kc0 = *(const f16x8*)kb;
    f16x8 kc1 = *(const f16x8*)(kb + 32);
    f16x4 vc[4];
#pragma unroll
    for (int ht = 0; ht < 4; ++ht) vc[ht] = *(const f16x4*)(vb + ht * 16 * SEQ);

#pragma unroll 2
    for (int g = 0; g < 64; ++g) {     // kv tiles of 16
        f16x8 kn0 = kc0, kn1 = kc1;
        f16x4 vn[4] = {vc[0], vc[1], vc[2], vc[3]};
        if (g < 63) {
            const short* kp = kb + (g + 1) * (16 * HD);
            kn0 = *(const f16x8*)kp;
            kn1 = *(const f16x8*)(kp + 32);
            const short* vp = vb + (g + 1) * 16;
#pragma unroll
            for (int ht = 0; ht < 4; ++ht) vn[ht] = *(const f16x4*)(vp + ht * 16 * SEQ);
        }
#pragma unroll
        for (int qt = 0; qt < 2; ++qt) {
            f32x4 s = (f32x4){0.f, 0.f, 0.f, 0.f};
            s = mfma32h(kc0, qf[qt][0], s);       // S^T[kv][q]
            s = mfma32h(kc1, qf[qt][1], s);
            float e0 = __builtin_amdgcn_exp2f(s[0] * EXP2_SCALE);
            float e1 = __builtin_amdgcn_exp2f(s[1] * EXP2_SCALE);
            float e2 = __builtin_amdgcn_exp2f(s[2] * EXP2_SCALE);
            float e3 = __builtin_amdgcn_exp2f(s[3] * EXP2_SCALE);
            psum[qt] += (e0 + e1) + (e2 + e3);
            U4 u;
            u.h2[0] = __builtin_amdgcn_cvt_pkrtz(e0, e1);
            u.h2[1] = __builtin_amdgcn_cvt_pkrtz(e2, e3);
#pragma unroll
            for (int ht = 0; ht < 4; ++ht)        // O^T[hd][q] += V^T * P^T
                oacc[qt][ht] = mfma16h(vc[ht], u.v, oacc[qt][ht]);
        }
        kc0 = kn0; kc1 = kn1;
#pragma unroll
        for (int ht = 0; ht < 4; ++ht) vc[ht] = vn[ht];
    }

    // full row sums: reduce partials across the 4 quads (lanes differing in bits 4,5)
#pragma unroll
    for (int qt = 0; qt < 2; ++qt) {
        psum[qt] += __shfl_xor(psum[qt], 16);
        psum[qt] += __shfl_xor(psum[qt], 32);
    }

    // epilogue: lane holds O[q=l15][hd=ht*16+quad*4+r] -> four 8B stores per q-tile
#pragma unroll
    for (int qt = 0; qt < 2; ++qt) {
        float rinv = 1.0f / psum[qt];
        short* orow = &O[((size_t)b * SEQ + q0 + qt * 16 + l15) * DIM + h * HD + quad * 4];
#pragma unroll
        for (int ht = 0; ht < 4; ++ht) {
            U4 u;
            u.h2[0] = __builtin_amdgcn_cvt_pkrtz(oacc[qt][ht][0] * rinv, oacc[qt][ht][1] * rinv);
            u.h2[1] = __builtin_amdgcn_cvt_pkrtz(oacc[qt][ht][2] * rinv, oacc[qt][ht][3] * rinv);
            *(f16x4*)(orow + ht * 16) = u.v;
        }
    }
}

extern "C" void kernel_launch(void* const* d_in, const int* in_sizes, int n_in,
                              void* d_out, int out_size, void* d_ws, size_t ws_size,
                              hipStream_t stream) {
    const float* x      = (const float*)d_in[0];
    const float* w_qkv  = (const float*)d_in[1];
    const float* w_proj = (const float*)d_in[2];
    const float* b_proj = (const float*)d_in[3];
    float* out = (float*)d_out;

    short* p = (short*)d_ws;
    short* Xb  = p; p += (size_t)M_TOTAL * DIM;
    short* Wqb = p; p += (size_t)QKV_OUT * DIM;
    short* Wpb = p; p += (size_t)DIM * DIM;
    short* Qb  = p; p += (size_t)B_SZ * NH * SEQ * HD;
    short* Kb  = p; p += (size_t)B_SZ * NH * SEQ * HD;
    short* Vtb = p; p += (size_t)B_SZ * NH * SEQ * HD;   // transposed [b][h][hd][n]
    short* Ob  = p; p += (size_t)M_TOTAL * DIM;

    cvt_kernel<<<1024, 256, 0, stream>>>(x, w_qkv, w_proj, Xb, Wqb, Wpb);
    gemm_bt<0, QKV_OUT, DIM><<<dim3(QKV_OUT / 128, M_TOTAL / 128), 256, 0, stream>>>(
        Xb, Wqb, Qb, Kb, Vtb, nullptr, nullptr);
    attn_kernel<<<B_SZ * NH * (SEQ / 128), 256, 0, stream>>>(Qb, Kb, Vtb, Ob);
    gemm_bt<1, DIM, DIM><<<dim3(DIM / 128, M_TOTAL / 128), 256, 0, stream>>>(
        Ob, Wpb, nullptr, nullptr, nullptr, out, b_proj);
}

// Round 7
// 401.456 us; speedup vs baseline: 1.1920x; 1.1920x over previous
//
#include <hip/hip_runtime.h>
#include <cstdint>

#define B_SZ 16
#define SEQ 1024
#define DIM 768
#define NH 12
#define HD 64
#define M_TOTAL (B_SZ*SEQ)       // 16384
#define QKV_OUT (3*DIM)          // 2304
#define EXP2_SCALE 0.18033688011f   // (1/8) * log2(e)

typedef _Float16 f16;
typedef __attribute__((ext_vector_type(8))) f16 f16x8;
typedef __attribute__((ext_vector_type(4))) f16 f16x4;
typedef __attribute__((ext_vector_type(2))) __fp16 pk16x2;   // cvt_pkrtz native type
typedef __attribute__((ext_vector_type(4))) short s4_t;
typedef __attribute__((ext_vector_type(4))) float f32x4;
typedef unsigned int u32;
typedef const __attribute__((address_space(1))) u32* gas_t;
typedef __attribute__((address_space(3))) u32* las_t;

union U4 { pk16x2 h2[2]; f16x4 v; };
union HS { f16 h; short s; };

__device__ __forceinline__ void async16(const void* g, void* l) {
    __builtin_amdgcn_global_load_lds((gas_t)g, (las_t)l, 16, 0, 0);
}
__device__ __forceinline__ f32x4 mfma32h(f16x8 a, f16x8 b, f32x4 c) {
    return __builtin_amdgcn_mfma_f32_16x16x32_f16(a, b, c, 0, 0, 0);
}
__device__ __forceinline__ f32x4 mfma16h(f16x4 a, f16x4 b, f32x4 c) {
    return __builtin_amdgcn_mfma_f32_16x16x16f16(a, b, c, 0, 0, 0);
}
__device__ __forceinline__ f16x8 ldfragh(const short* p) {
    return *(const f16x8*)p;
}

// ---------------- fp32 -> fp16 conversion of x, w_qkv, w_proj ----------------
__global__ void cvt_kernel(const float* __restrict__ x, const float* __restrict__ wq,
                           const float* __restrict__ wp,
                           short* __restrict__ xb, short* __restrict__ wqb, short* __restrict__ wpb) {
    const long nx = (long)M_TOTAL * DIM / 4;
    const long nq = (long)QKV_OUT * DIM / 4;
    const long np = (long)DIM * DIM / 4;
    const long total = nx + nq + np;
    for (long i = (long)blockIdx.x * blockDim.x + threadIdx.x; i < total;
         i += (long)gridDim.x * blockDim.x) {
        const float4* src; short* dst; long off;
        if (i < nx)            { src = (const float4*)x;  dst = xb;  off = i; }
        else if (i < nx + nq)  { src = (const float4*)wq; dst = wqb; off = i - nx; }
        else                   { src = (const float4*)wp; dst = wpb; off = i - nx - nq; }
        float4 v = src[off];
        U4 u;
        u.h2[0] = __builtin_amdgcn_cvt_pkrtz(v.x, v.y);
        u.h2[1] = __builtin_amdgcn_cvt_pkrtz(v.z, v.w);
        *(f16x4*)(dst + off * 4) = u.v;
    }
}

// ---------------- m97-style f16 GEMM:  C[M,N] = A[M,K] * Bm[N,K]^T ----------------
// EPI 0: scatter to Q/K [b][h][n][hd] and V TRANSPOSED [b][h][hd][n]
// EPI 1: add bias, write fp32 to Cout [M,N]
template<int EPI, int N, int K>
__global__ __launch_bounds__(256) void gemm_bt(const short* __restrict__ A,
                                               const short* __restrict__ Bm,
                                               short* __restrict__ Cq, short* __restrict__ Ck,
                                               short* __restrict__ Cv,
                                               float* __restrict__ Cout,
                                               const float* __restrict__ bias) {
    __shared__ short As[128 * 32];
    __shared__ short Bs[128 * 32];
    const int tid = threadIdx.x;
    const int w = tid >> 6, l = tid & 63, quad = l >> 4, l15 = l & 15;
    const int wr = w >> 1, wc = w & 1;
    const int m0 = blockIdx.y * 128, n0 = blockIdx.x * 128;

    f32x4 acc[4][4];
#pragma unroll
    for (int i = 0; i < 4; ++i)
#pragma unroll
        for (int j = 0; j < 4; ++j) acc[i][j] = (f32x4){0.f, 0.f, 0.f, 0.f};

    for (int kt = 0; kt < K / 32; ++kt) {
#pragma unroll
        for (int i = 0; i < 2; ++i) {
            int c = i * 256 + tid;
            int row = c >> 2, kc = c & 3;
            async16(&A[(size_t)(m0 + row) * K + kt * 32 + kc * 8], &As[c * 8]);
            async16(&Bm[(size_t)(n0 + row) * K + kt * 32 + kc * 8], &Bs[c * 8]);
        }
        __syncthreads();
        f16x8 af[4], bf[4];
#pragma unroll
        for (int rt = 0; rt < 4; ++rt)
            af[rt] = ldfragh(&As[(wr * 64 + rt * 16 + l15) * 32 + quad * 8]);
#pragma unroll
        for (int ct = 0; ct < 4; ++ct)
            bf[ct] = ldfragh(&Bs[(wc * 64 + ct * 16 + l15) * 32 + quad * 8]);
#pragma unroll
        for (int rt = 0; rt < 4; ++rt)
#pragma unroll
            for (int ct = 0; ct < 4; ++ct)
                acc[rt][ct] = mfma32h(af[rt], bf[ct], acc[rt][ct]);
        __syncthreads();
    }

#pragma unroll
    for (int rt = 0; rt < 4; ++rt) {
#pragma unroll
        for (int ct = 0; ct < 4; ++ct) {
            int col = n0 + wc * 64 + ct * 16 + l15;
            if (EPI == 0) {
                int s = col / DIM;
                int h = (col - s * DIM) >> 6, hd = col & 63;
                int mbase = m0 + wr * 64 + rt * 16 + quad * 4;
                int b = mbase >> 10, nn = mbase & 1023;
                if (s == 2) {
                    // V transposed: [b][h][hd][n]; 4 consecutive n -> one 8B store
                    U4 u;
                    u.h2[0] = __builtin_amdgcn_cvt_pkrtz(acc[rt][ct][0], acc[rt][ct][1]);
                    u.h2[1] = __builtin_amdgcn_cvt_pkrtz(acc[rt][ct][2], acc[rt][ct][3]);
                    *(f16x4*)&Cv[(((size_t)b * NH + h) * HD + hd) * SEQ + nn] = u.v;
                } else {
                    short* dst = (s == 0) ? Cq : Ck;
#pragma unroll
                    for (int r = 0; r < 4; ++r) {
                        HS t; t.h = (f16)acc[rt][ct][r];
                        dst[(((size_t)b * NH + h) * SEQ + nn + r) * HD + hd] = t.s;
                    }
                }
            } else {
                float bv = bias[col];
#pragma unroll
                for (int r = 0; r < 4; ++r) {
                    int m = m0 + wr * 64 + rt * 16 + quad * 4 + r;
                    Cout[(size_t)m * N + col] = acc[rt][ct][r] + bv;
                }
            }
        }
    }
}

// ---------------- attention: register flash, 2-stage pipelined, all-16B loads -------
// S^T = K*Q^T trick (C/D of S^T == B-operand layout of 16x16x16 PV MFMA). kv processed
// in 32-blocks split into permuted tiles A={8q+j}, B={8q+4+j}: K rows loaded in that
// order (per-lane gather, free) so ONE f16x8 V^T load at col 8*quad feeds both PV
// fragments (lo half->tile A, hi half->tile B) -> every global load is dwordx4.
// Whole-block K/V register double-buffer: 8 loads in flight one block ahead.
__global__ __launch_bounds__(256) void attn_kernel(const short* __restrict__ Q,
                                                   const short* __restrict__ Km,
                                                   const short* __restrict__ Vt,
                                                   short* __restrict__ O) {
    const int tid = threadIdx.x;
    const int w = tid >> 6, l = tid & 63, quad = l >> 4, l15 = l & 15;
    const int bid = blockIdx.x;
    const int xcd = bid & 7, kk = bid >> 3;
    const int head = xcd + 8 * (kk >> 3);        // 0..191, 8 q-chunks/head per XCD
    const int q0 = (kk & 7) * 128 + w * 32;      // this wave's 32 q rows
    const int b = head / NH, h = head - b * NH;
    const short* Qp = Q + (size_t)head * (SEQ * HD);
    const short* Kp = Km + (size_t)head * (SEQ * HD);
    const short* Vp = Vt + (size_t)head * (SEQ * HD);   // [hd][n]

    // Q as B-operand fragments: B[n=q=l15][k=hd=quad*8+j], two hd-halves, two q-tiles
    f16x8 qf[2][2];
#pragma unroll
    for (int qt = 0; qt < 2; ++qt)
#pragma unroll
        for (int hf = 0; hf < 2; ++hf)
            qf[qt][hf] = *(const f16x8*)&Qp[(q0 + qt * 16 + l15) * HD + hf * 32 + quad * 8];

    f32x4 oacc[2][4];
#pragma unroll
    for (int qt = 0; qt < 2; ++qt)
#pragma unroll
        for (int ht = 0; ht < 4; ++ht) oacc[qt][ht] = (f32x4){0.f, 0.f, 0.f, 0.f};
    float psum[2] = {0.f, 0.f};

    // permuted K row for tile A: lane l15 -> kv = 8*(l15>>2) + (l15&3); tile B: +4
    const int krowA = 8 * (l15 >> 2) + (l15 & 3);
    const short* kbA = &Kp[krowA * HD + quad * 8];          // + g*32*HD per block
    const short* kbB = kbA + 4 * HD;
    // V^T: lane l15 -> hd row (ht*16+l15); col = 8*quad within the 32-kv block
    const short* vb0 = &Vp[(0 * 16 + l15) * SEQ + quad * 8];
    const short* vb1 = &Vp[(1 * 16 + l15) * SEQ + quad * 8];
    const short* vb2 = &Vp[(2 * 16 + l15) * SEQ + quad * 8];
    const short* vb3 = &Vp[(3 * 16 + l15) * SEQ + quad * 8];

    // 2-stage register pipeline over 32 blocks of 32 kv
    f16x8 kA0[2], kA1[2], kB0[2], kB1[2], vv[2][4];
#define LOADBLK(st, g) do {                                               \
        const int koff = (g) * 32 * HD;                                   \
        kA0[st] = *(const f16x8*)(kbA + koff);                            \
        kA1[st] = *(const f16x8*)(kbA + koff + 32);                       \
        kB0[st] = *(const f16x8*)(kbB + koff);                            \
        kB1[st] = *(const f16x8*)(kbB + koff + 32);                       \
        const int voff = (g) * 32;                                        \
        vv[st][0] = *(const f16x8*)(vb0 + voff);                          \
        vv[st][1] = *(const f16x8*)(vb1 + voff);                          \
        vv[st][2] = *(const f16x8*)(vb2 + voff);                          \
        vv[st][3] = *(const f16x8*)(vb3 + voff);                          \
    } while (0)

    LOADBLK(0, 0);
#pragma unroll 2
    for (int g = 0; g < 32; ++g) {
        const int cur = g & 1, nxt = cur ^ 1;
        if (g < 31) LOADBLK(nxt, g + 1);
#pragma unroll
        for (int qt = 0; qt < 2; ++qt) {
            f32x4 sA = (f32x4){0.f, 0.f, 0.f, 0.f};
            sA = mfma32h(kA0[cur], qf[qt][0], sA);
            sA = mfma32h(kA1[cur], qf[qt][1], sA);
            f32x4 sB = (f32x4){0.f, 0.f, 0.f, 0.f};
            sB = mfma32h(kB0[cur], qf[qt][0], sB);
            sB = mfma32h(kB1[cur], qf[qt][1], sB);
            float eA0 = __builtin_amdgcn_exp2f(sA[0] * EXP2_SCALE);
            float eA1 = __builtin_amdgcn_exp2f(sA[1] * EXP2_SCALE);
            float eA2 = __builtin_amdgcn_exp2f(sA[2] * EXP2_SCALE);
            float eA3 = __builtin_amdgcn_exp2f(sA[3] * EXP2_SCALE);
            float eB0 = __builtin_amdgcn_exp2f(sB[0] * EXP2_SCALE);
            float eB1 = __builtin_amdgcn_exp2f(sB[1] * EXP2_SCALE);
            float eB2 = __builtin_amdgcn_exp2f(sB[2] * EXP2_SCALE);
            float eB3 = __builtin_amdgcn_exp2f(sB[3] * EXP2_SCALE);
            psum[qt] += ((eA0 + eA1) + (eA2 + eA3)) + ((eB0 + eB1) + (eB2 + eB3));
            U4 uA, uB;
            uA.h2[0] = __builtin_amdgcn_cvt_pkrtz(eA0, eA1);
            uA.h2[1] = __builtin_amdgcn_cvt_pkrtz(eA2, eA3);
            uB.h2[0] = __builtin_amdgcn_cvt_pkrtz(eB0, eB1);
            uB.h2[1] = __builtin_amdgcn_cvt_pkrtz(eB2, eB3);
#pragma unroll
            for (int ht = 0; ht < 4; ++ht) {
                f16x4 vlo = __builtin_shufflevector(vv[cur][ht], vv[cur][ht], 0, 1, 2, 3);
                f16x4 vhi = __builtin_shufflevector(vv[cur][ht], vv[cur][ht], 4, 5, 6, 7);
                oacc[qt][ht] = mfma16h(vlo, uA.v, oacc[qt][ht]);   // tile A: kv = 8q+j
                oacc[qt][ht] = mfma16h(vhi, uB.v, oacc[qt][ht]);   // tile B: kv = 8q+4+j
            }
        }
    }
#undef LOADBLK

    // full row sums: reduce partials across the 4 quads (lanes differing in bits 4,5)
#pragma unroll
    for (int qt = 0; qt < 2; ++qt) {
        psum[qt] += __shfl_xor(psum[qt], 16);
        psum[qt] += __shfl_xor(psum[qt], 32);
    }

    // epilogue: lane holds O[q=l15][hd=ht*16+quad*4+r] -> four 8B stores per q-tile
#pragma unroll
    for (int qt = 0; qt < 2; ++qt) {
        float rinv = 1.0f / psum[qt];
        short* orow = &O[((size_t)b * SEQ + q0 + qt * 16 + l15) * DIM + h * HD + quad * 4];
#pragma unroll
        for (int ht = 0; ht < 4; ++ht) {
            U4 u;
            u.h2[0] = __builtin_amdgcn_cvt_pkrtz(oacc[qt][ht][0] * rinv, oacc[qt][ht][1] * rinv);
            u.h2[1] = __builtin_amdgcn_cvt_pkrtz(oacc[qt][ht][2] * rinv, oacc[qt][ht][3] * rinv);
            *(f16x4*)(orow + ht * 16) = u.v;
        }
    }
}

extern "C" void kernel_launch(void* const* d_in, const int* in_sizes, int n_in,
                              void* d_out, int out_size, void* d_ws, size_t ws_size,
                              hipStream_t stream) {
    const float* x      = (const float*)d_in[0];
    const float* w_qkv  = (const float*)d_in[1];
    const float* w_proj = (const float*)d_in[2];
    const float* b_proj = (const float*)d_in[3];
    float* out = (float*)d_out;

    short* p = (short*)d_ws;
    short* Xb  = p; p += (size_t)M_TOTAL * DIM;
    short* Wqb = p; p += (size_t)QKV_OUT * DIM;
    short* Wpb = p; p += (size_t)DIM * DIM;
    short* Qb  = p; p += (size_t)B_SZ * NH * SEQ * HD;
    short* Kb  = p; p += (size_t)B_SZ * NH * SEQ * HD;
    short* Vtb = p; p += (size_t)B_SZ * NH * SEQ * HD;   // transposed [b][h][hd][n]
    short* Ob  = p; p += (size_t)M_TOTAL * DIM;

    cvt_kernel<<<1024, 256, 0, stream>>>(x, w_qkv, w_proj, Xb, Wqb, Wpb);
    gemm_bt<0, QKV_OUT, DIM><<<dim3(QKV_OUT / 128, M_TOTAL / 128), 256, 0, stream>>>(
        Xb, Wqb, Qb, Kb, Vtb, nullptr, nullptr);
    attn_kernel<<<B_SZ * NH * (SEQ / 128), 256, 0, stream>>>(Qb, Kb, Vtb, Ob);
    gemm_bt<1, DIM, DIM><<<dim3(DIM / 128, M_TOTAL / 128), 256, 0, stream>>>(
        Ob, Wpb, nullptr, nullptr, nullptr, out, b_proj);
}